// Round 12
// baseline (260.452 us; speedup 1.0000x reference)
//
#include <hip/hip_runtime.h>
#include <hip/hip_bf16.h>

typedef _Float16 f16;
typedef f16  f16x8 __attribute__((ext_vector_type(8)));
typedef float f32x4 __attribute__((ext_vector_type(4)));
typedef float f32x16 __attribute__((ext_vector_type(16)));

// ---------------- workspace layout ----------------
// h1p  : [256][13][196] f32
// Wb2  : [13cg][13ky][13kx][64l][8] f16   conv2 B-frags (32x32x16: K=16ch)
// Wf1b : [33ks][26kstep][6nt][64l][8] f16
// Pp   : [4q][256b][7mt][32r][32o] f32    conv2 tap-quarter partials
// h2f  : [256][1029] f32
// P3   : [33][256][89] f32
static constexpr size_t H1_OFF = 0;
static constexpr size_t H1_BYTES = (size_t)256 * 13 * 196 * 4;            // 2,609,152
static constexpr size_t WB_OFF = H1_OFF + H1_BYTES;
static constexpr size_t WB_BYTES = (size_t)2197 * 64 * 8 * 2;             // 2,249,728
static constexpr size_t WF_OFF = WB_OFF + WB_BYTES;
static constexpr size_t WF_BYTES = (size_t)33 * 26 * 6 * 64 * 8 * 2;      // 5,271,552
static constexpr size_t PP_OFF = WF_OFF + WF_BYTES;
static constexpr size_t PP_BYTES = (size_t)4 * 256 * 7 * 32 * 32 * 4;     // 29,360,128
static constexpr size_t H2_OFF = PP_OFF + PP_BYTES;
static constexpr size_t H2_BYTES = (size_t)256 * 1029 * 4;                // 1,053,696
static constexpr size_t P3_OFF = H2_OFF + H2_BYTES;

static constexpr int NCH = 33;

// ------------------------------------------------------------------
// K0: conv2 B-frags for mfma_f32_32x32x16_f16.
// ------------------------------------------------------------------
__global__ __launch_bounds__(256) void k_prep_wb(const float* __restrict__ w2,
                                                 f16* __restrict__ Wb2) {
    int idx = blockIdx.x * 256 + threadIdx.x;   // 2197*64 = 140,608
    if (idx >= 2197 * 64) return;
    int l = idx & 63; int frag = idx >> 6;
    int kx = frag % 13; int t2 = frag / 13;
    int ky = t2 % 13; int cg = t2 / 13;
    int o = l & 31;
    f16x8 v;
#pragma unroll
    for (int i = 0; i < 8; ++i) {
        float wv = 0.f;
        if (o < 21) {
            int ch = cg * 16 + (l >> 5) * 8 + i;
            int c2 = ch / 104, rr = ch % 104, ii = rr >> 3, gg = rr & 7;
            wv = w2[(size_t)(c2 * 21 + o) * 17576 + ii * 1352 + ky * 104 + kx * 8 + gg];
        }
        v[i] = (f16)wv;
    }
    *(f16x8*)&Wb2[(size_t)idx * 8] = v;
}

// ------------------------------------------------------------------
// K0b: fk1 B-fragments, coalesced via LDS transpose.
// ------------------------------------------------------------------
__global__ __launch_bounds__(256) void k_prep_wf(const float* __restrict__ wf1,
                                                 f16* __restrict__ Wf1b) {
    __shared__ __align__(16) f16 Wl[13][2848];
    int bid = blockIdx.x;          // 66 = 33 ks x 2 c
    int c = bid & 1, ks = bid >> 1;
    int tid = threadIdx.x;
    for (int e = tid; e < 89 * 32; e += 256) {
        int o = e >> 5, dl = e & 31;
        int d = ks * 32 + dl;
        if (d < 1029) {
            const float* p = wf1 + ((size_t)(c * 89 + o) * 1029 + d) * 13;
#pragma unroll
            for (int g = 0; g < 13; ++g) Wl[g][e] = (f16)p[g];
        } else {
#pragma unroll
            for (int g = 0; g < 13; ++g) Wl[g][e] = (f16)0;
        }
    }
    __syncthreads();
    for (int t = tid; t < 13 * 6 * 64; t += 256) {
        int l = t & 63; int q = t >> 6; int nt = q % 6; int g = q / 6;
        int o = nt * 16 + (l & 15);
        int kbase = (l >> 4) * 8;
        f16x8 v;
#pragma unroll
        for (int i = 0; i < 8; ++i)
            v[i] = (o < 89) ? Wl[g][o * 32 + kbase + i] : (f16)0;
        *(f16x8*)&Wf1b[(((size_t)ks * 26 + c * 13 + g) * 6 + nt) * 512 + (size_t)l * 8] = v;
    }
}

// ------------------------------------------------------------------
// K1: conv1 (unchanged).
// ------------------------------------------------------------------
__global__ __launch_bounds__(256) void k_conv1(const float* __restrict__ x,
                                               const float* __restrict__ w1,
                                               const float* __restrict__ b1,
                                               float* __restrict__ h1p) {
    __shared__ float2 tcs[5][448];
    __shared__ float  cv[392 * 13];
    int bid = blockIdx.x, tid = threadIdx.x;
    int b = bid >> 1, yh = bid & 1;
    int y0 = yh * 12;
    const float* xb = x + (size_t)b * 784;
    for (int i = tid; i < 448; i += 256) {
        float v = xb[y0 * 28 + i];
        float s1, c1; __sincosf(v, &s1, &c1);
        float ck = c1, sk = s1, ckm = 1.f, skm = 0.f;
#pragma unroll
        for (int g = 0; g < 5; ++g) {
            tcs[g][i] = make_float2(ck, sk);
            float cn = 2.f * c1 * ck - ckm, sn = 2.f * c1 * sk - skm;
            ckm = ck; ck = cn; skm = sk; sk = sn;
        }
    }
    __syncthreads();
    for (int pp = tid; pp < 392; pp += 256) {
        int yl = pp / 28, xx = pp % 28;
        int y = yh * 14 + yl;
        float acc[13] = {};
        for (int ky = 0; ky < 5; ++ky) {
            int row = y + ky - 2;
            if ((unsigned)row >= 28u) continue;
            int lr = row - y0;
            for (int kx = 0; kx < 5; ++kx) {
                int col = xx + kx - 2;
                if ((unsigned)col >= 28u) continue;
                float2 tv[5];
#pragma unroll
                for (int g = 0; g < 5; ++g) tv[g] = tcs[g][lr * 28 + col];
#pragma unroll
                for (int o = 0; o < 13; ++o) {
                    const float* wco = w1 + (o * 25 + ky * 5 + kx) * 5;
                    const float* wso = wco + 1625;
                    float a = acc[o];
#pragma unroll
                    for (int g = 0; g < 5; ++g)
                        a = fmaf(tv[g].x, wco[g], fmaf(tv[g].y, wso[g], a));
                    acc[o] = a;
                }
            }
        }
#pragma unroll
        for (int o = 0; o < 13; ++o) cv[pp * 13 + o] = acc[o];
    }
    __syncthreads();
    for (int i = tid; i < 7 * 14 * 13; i += 256) {
        int o = i % 13; int r = i / 13; int px = r % 14; int pyl = r / 14;
        int base0 = ((pyl * 2) * 28 + px * 2) * 13 + o;
        float m = fmaxf(fmaxf(cv[base0], cv[base0 + 13]),
                        fmaxf(cv[base0 + 28 * 13], cv[base0 + 28 * 13 + 13]));
        int py = yh * 7 + pyl;
        h1p[((size_t)b * 13 + o) * 196 + py * 14 + px] = m + b1[o];
    }
}

// ------------------------------------------------------------------
// K2: conv2 via mfma_f32_32x32x16_f16.
// CHANGE vs round 11: Tl layout [yy][oct][xx] (16B cells).  A-read
// lanes (consecutive px) now stride 16B -> every 8-lane b128 phase
// covers all 32 banks once (was 32B stride = half banks, 2 lanes/bank
// -> 8.2M conflict cycles).  Staging reindexed for contiguous writes.
// ------------------------------------------------------------------
__global__ __launch_bounds__(256, 2) void k_conv2m(const float* __restrict__ h1p,
                                                   const f16* __restrict__ Wb2,
                                                   float* __restrict__ Pp) {
    __shared__ f16 Tl[28 * 2 * 32 * 8];   // [yy][oc][xx] cells of 8 f16 = 28,672 B
    const int bid = blockIdx.x;
    const int b = bid >> 2, q = bid & 3;
    const int tid = threadIdx.x;
    const int l = tid & 63, w = tid >> 6;
    const int oct = l >> 5;            // k-half (8 ch) -> oc slot
    const int pyb = (l >> 4) & 1;      // row within pair
    const int px = l & 15;

    // zero halo once: cells (yy,oc,xx), yy<6||yy>=20||xx<6||xx>=20
    for (int pos = tid; pos < 1792; pos += 256) {
        int yy2 = pos >> 5, xx = pos & 31;   // yy2 = yy*2+oc
        int yy = yy2 >> 1;
        if (yy < 6 || yy >= 20 || xx < 6 || xx >= 20) {
            f16x8 z = {};
            *(f16x8*)&Tl[(yy2 * 32 + xx) * 8] = z;
        }
    }

    f32x16 acc[7] = {};

    for (int cg = 0; cg < 13; ++cg) {
        if (cg) __syncthreads();           // prior reads done before overwrite
        // stage: j<196 -> oc=0, else oc=1; contiguous 16B writes per run
        for (int j = tid; j < 392; j += 256) {
            int oc = (j >= 196), p = j - oc * 196;
            int ch0 = cg * 16 + oc * 8;
            int c2 = ch0 / 104, rr = ch0 % 104, ii = rr >> 3;
            float h = h1p[((size_t)b * 13 + ii) * 196 + p];
            float s1, c1; __sincosf(h, &s1, &c1);
            f16x8 v;
            float ck = c1, sk = s1, ckm = 1.f, skm = 0.f;
#pragma unroll
            for (int g = 0; g < 8; ++g) {
                v[g] = (f16)(c2 == 0 ? ck : sk);
                float cn = 2.f * c1 * ck - ckm;
                float sn2 = 2.f * c1 * sk - skm;
                ckm = ck; ck = cn; skm = sk; sk = sn2;
            }
            int y = p / 14, xp = p - y * 14;
            *(f16x8*)&Tl[((((y + 6) * 2 + oc) * 32) + xp + 6) * 8] = v;
        }
        __syncthreads();

        const int j0 = (w + cg) & 3;
        for (int kxs = 0; kxs < 4; ++kxs) {
            const int kx = j0 + kxs * 4;
            if (kx > 12) break;            // uniform per wave
            f16x8 bf[4];
#pragma unroll
            for (int t = 0; t < 3; ++t)
                bf[t] = *(const f16x8*)&Wb2[(((size_t)(cg * 13 + (q + 4 * t)) * 13 + kx) * 64 + l) * 8];
            if (q == 0)
                bf[3] = *(const f16x8*)&Wb2[(((size_t)(cg * 13 + 12) * 13 + kx) * 64 + l) * 8];
            const int xx = px + kx;
#pragma unroll
            for (int kp = 0; kp < 13; ++kp) {     // r = q + 2*kp
                if (kp >= 11 && q != 0) continue; // only t=3 serves kp 11,12
                const int yy = q + 2 * kp + pyb;
                f16x8 a = *(const f16x8*)&Tl[(((yy * 2 + oct) * 32) + xx) * 8];
#pragma unroll
                for (int t = 0; t < 4; ++t) {
                    const int mt = kp - 2 * t;
                    if (mt >= 0 && mt <= 6) {
                        if (t < 3)
                            acc[mt] = __builtin_amdgcn_mfma_f32_32x32x16_f16(a, bf[t], acc[mt], 0, 0, 0);
                        else if (q == 0)
                            acc[mt] = __builtin_amdgcn_mfma_f32_32x32x16_f16(a, bf[3], acc[mt], 0, 0, 0);
                    }
                }
            }
        }
    }

    // 4-wave LDS reduction into R[7][32][32] (reuses Tl)
    __syncthreads();
    float* R = (float*)&Tl[0];
    for (int ph = 0; ph < 4; ++ph) {
        if (w == ph) {
#pragma unroll
            for (int mt = 0; mt < 7; ++mt)
#pragma unroll
                for (int reg = 0; reg < 16; ++reg) {
                    int row = (reg & 3) + 8 * (reg >> 2) + 4 * oct;
                    int idx = (mt * 32 + row) * 32 + (l & 31);
                    float v = acc[mt][reg];
                    if (ph) v += R[idx];
                    R[idx] = v;
                }
        }
        __syncthreads();
    }
    float* P = Pp + (size_t)(q * 256 + b) * 7168;
    for (int i = tid; i < 7168; i += 256) P[i] = R[i];
}

// ------------------------------------------------------------------
// K3: sum 4 tap-quarter partials + maxpool + bias -> h2f
// ------------------------------------------------------------------
__global__ __launch_bounds__(256) void k_pool2(const float* __restrict__ Pp,
                                               const float* __restrict__ b2,
                                               float* __restrict__ h2f) {
    int b = blockIdx.x, tid = threadIdx.x;
    for (int idx = tid; idx < 1029; idx += 256) {
        int o = idx % 21; int r = idx / 21; int px = r % 7; int py = r / 7;
        float mx = -1e30f;
#pragma unroll
        for (int sy = 0; sy < 2; ++sy)
#pragma unroll
            for (int sx = 0; sx < 2; ++sx) {
                int py2 = 2 * py + sy, px2 = 2 * px + sx;
                int mt = py2 >> 1, rr = (py2 & 1) * 16 + px2;
                float v = 0.f;
#pragma unroll
                for (int qq = 0; qq < 4; ++qq)
                    v += Pp[(size_t)(qq * 256 + b) * 7168 + (mt * 32 + rr) * 32 + o];
                mx = fmaxf(mx, v);
            }
        h2f[(size_t)b * 1029 + o * 49 + py * 7 + px] = mx + b2[o];
    }
}

// ------------------------------------------------------------------
// K4: fk1 via MFMA (unchanged).
// ------------------------------------------------------------------
__global__ __launch_bounds__(256) void k_fk1m(const float* __restrict__ h2f,
                                              const f16* __restrict__ Wf1b,
                                              float* __restrict__ P3) {
    __shared__ f16 A[26 * 32 * 32];
    const int bid = blockIdx.x;
    const int mt8 = bid / NCH, ks = bid % NCH;
    const int m0 = mt8 * 32, d0 = ks * 32;
    const int tid = threadIdx.x;
    const int dl = tid & 31, mb = tid >> 5;
#pragma unroll
    for (int j = 0; j < 4; ++j) {
        int m = mb + 8 * j;
        int d = d0 + dl;
        bool valid = d < 1029;
        float h = valid ? h2f[(size_t)(m0 + m) * 1029 + d] : 0.f;
        float s1, c1; __sincosf(h, &s1, &c1);
        float ck = c1, sk = s1, ckm = 1.f, skm = 0.f;
#pragma unroll
        for (int g = 0; g < 13; ++g) {
            A[(g) * 1024 + m * 32 + dl]      = valid ? (f16)ck : (f16)0;
            A[(13 + g) * 1024 + m * 32 + dl] = valid ? (f16)sk : (f16)0;
            float cn = 2.f * c1 * ck - ckm;
            float sn2 = 2.f * c1 * sk - skm;
            ckm = ck; ck = cn; skm = sk; sk = sn2;
        }
    }
    __syncthreads();
    const int w = tid >> 6, l = tid & 63;
    const int mt = w >> 1, ntg = (w & 1) * 3;
    f32x4 acc[3] = {};
    for (int kstep = 0; kstep < 26; ++kstep) {
        f16x8 a = *(const f16x8*)&A[kstep * 1024 + (mt * 16 + (l & 15)) * 32 + (l >> 4) * 8];
#pragma unroll
        for (int j = 0; j < 3; ++j) {
            f16x8 bv = *(const f16x8*)&Wf1b[((((size_t)ks * 26 + kstep) * 6 + ntg + j) * 64 + l) * 8];
            acc[j] = __builtin_amdgcn_mfma_f32_16x16x32_f16(a, bv, acc[j], 0, 0, 0);
        }
    }
    const int o_base = (l & 15);
#pragma unroll
    for (int j = 0; j < 3; ++j) {
        int o = (ntg + j) * 16 + o_base;
        if (o < 89) {
#pragma unroll
            for (int jj = 0; jj < 4; ++jj) {
                int m = m0 + mt * 16 + (l >> 4) * 4 + jj;
                P3[((size_t)ks * 256 + m) * 89 + o] = acc[j][jj];
            }
        }
    }
}

// ------------------------------------------------------------------
// K5: reduce 33 fk1 partials + bias -> trig(G=8) -> fk2 -> f32 out
// ------------------------------------------------------------------
__global__ __launch_bounds__(128) void k_fk2(const float* __restrict__ P3,
                                             const float* __restrict__ bias1,
                                             const float* __restrict__ wf2,
                                             const float* __restrict__ bias2,
                                             float* __restrict__ out) {
    __shared__ float2 tcs2[89][8];
    __shared__ float part[80];
    int b = blockIdx.x, tid = threadIdx.x;
    if (tid < 89) {
        float v = bias1[tid];
        for (int ks = 0; ks < NCH; ++ks)
            v += P3[((size_t)ks * 256 + b) * 89 + tid];
#pragma unroll
        for (int g = 0; g < 8; ++g) {
            float s, c; __sincosf(v * (float)(g + 1), &s, &c);
            tcs2[tid][g] = make_float2(c, s);
        }
    }
    __syncthreads();
    if (tid < 80) {
        int o = tid >> 3, g = tid & 7;
        float s = 0.f;
        for (int d = 0; d < 89; ++d) {
            float2 tv = tcs2[d][g];
            s = fmaf(tv.x, wf2[((size_t)o * 89 + d) * 8 + g],
                fmaf(tv.y, wf2[7120 + ((size_t)o * 89 + d) * 8 + g], s));
        }
        part[tid] = s;
    }
    __syncthreads();
    if (tid < 10) {
        float v = bias2[tid];
#pragma unroll
        for (int g = 0; g < 8; ++g) v += part[tid * 8 + g];
        out[b * 10 + tid] = v;
    }
}

extern "C" void kernel_launch(void* const* d_in, const int* in_sizes, int n_in,
                              void* d_out, int out_size, void* d_ws, size_t ws_size,
                              hipStream_t stream) {
    const float* x   = (const float*)d_in[0];
    const float* w1  = (const float*)d_in[1];
    const float* b1  = (const float*)d_in[2];
    const float* w2  = (const float*)d_in[3];
    const float* b2  = (const float*)d_in[4];
    const float* wf1 = (const float*)d_in[5];
    const float* bf1 = (const float*)d_in[6];
    const float* wf2 = (const float*)d_in[7];
    const float* bf2v = (const float*)d_in[8];

    char* ws  = (char*)d_ws;
    float* h1p  = (float*)(ws + H1_OFF);
    f16*   Wb2  = (f16*)(ws + WB_OFF);
    f16*   Wf1b = (f16*)(ws + WF_OFF);
    float* Pp   = (float*)(ws + PP_OFF);
    float* h2f  = (float*)(ws + H2_OFF);
    float* P3   = (float*)(ws + P3_OFF);

    k_prep_wb<<<(2197 * 64 + 255) / 256, 256, 0, stream>>>(w2, Wb2);
    k_prep_wf<<<66, 256, 0, stream>>>(wf1, Wf1b);
    k_conv1<<<512, 256, 0, stream>>>(x, w1, b1, h1p);
    k_conv2m<<<1024, 256, 0, stream>>>(h1p, Wb2, Pp);
    k_pool2<<<256, 256, 0, stream>>>(Pp, b2, h2f);
    k_fk1m<<<8 * NCH, 256, 0, stream>>>(h2f, Wf1b, P3);
    k_fk2<<<256, 128, 0, stream>>>(P3, bf1, wf2, bf2v, (float*)d_out);
}

// Round 13
// 231.208 us; speedup vs baseline: 1.1265x; 1.1265x over previous
//
#include <hip/hip_runtime.h>
#include <hip/hip_bf16.h>

typedef _Float16 f16;
typedef f16  f16x8 __attribute__((ext_vector_type(8)));
typedef float f32x4 __attribute__((ext_vector_type(4)));
typedef float f32x16 __attribute__((ext_vector_type(16)));

// ---------------- workspace layout ----------------
// Tpre : [256][26(c,i)][196p][8g] f16  pooled-trig, ready for conv2 staging
// Wb2  : [13cg][13ky][13kx][64l][8] f16
// Wf1b : [33ks][26kstep][6nt][64l][8] f16
// Pp   : [2par][256b][7mt][32r][32o] f32
// h2f  : [256][1029] f32
// P3   : [33][256][89] f32
static constexpr size_t TP_OFF = 0;
static constexpr size_t TP_BYTES = (size_t)256 * 26 * 196 * 8 * 2;        // 20,873,216
static constexpr size_t WB_OFF = TP_OFF + TP_BYTES;
static constexpr size_t WB_BYTES = (size_t)2197 * 64 * 8 * 2;             // 2,249,728
static constexpr size_t WF_OFF = WB_OFF + WB_BYTES;
static constexpr size_t WF_BYTES = (size_t)33 * 26 * 6 * 64 * 8 * 2;      // 5,271,552
static constexpr size_t PP_OFF = WF_OFF + WF_BYTES;
static constexpr size_t PP_BYTES = (size_t)2 * 256 * 7 * 32 * 32 * 4;     // 14,680,064
static constexpr size_t H2_OFF = PP_OFF + PP_BYTES;
static constexpr size_t H2_BYTES = (size_t)256 * 1029 * 4;                // 1,053,696
static constexpr size_t P3_OFF = H2_OFF + H2_BYTES;

static constexpr int NCH = 33;

// ------------------------------------------------------------------
// K0: conv2 B-frags for mfma_f32_32x32x16_f16 (unchanged).
// ------------------------------------------------------------------
__global__ __launch_bounds__(256) void k_prep_wb(const float* __restrict__ w2,
                                                 f16* __restrict__ Wb2) {
    int idx = blockIdx.x * 256 + threadIdx.x;   // 2197*64 = 140,608
    if (idx >= 2197 * 64) return;
    int l = idx & 63; int frag = idx >> 6;
    int kx = frag % 13; int t2 = frag / 13;
    int ky = t2 % 13; int cg = t2 / 13;
    int o = l & 31;
    f16x8 v;
#pragma unroll
    for (int i = 0; i < 8; ++i) {
        float wv = 0.f;
        if (o < 21) {
            int ch = cg * 16 + (l >> 5) * 8 + i;
            int c2 = ch / 104, rr = ch % 104, ii = rr >> 3, gg = rr & 7;
            wv = w2[(size_t)(c2 * 21 + o) * 17576 + ii * 1352 + ky * 104 + kx * 8 + gg];
        }
        v[i] = (f16)wv;
    }
    *(f16x8*)&Wb2[(size_t)idx * 8] = v;
}

// ------------------------------------------------------------------
// K0b: fk1 B-fragments, coalesced via LDS transpose (unchanged).
// ------------------------------------------------------------------
__global__ __launch_bounds__(256) void k_prep_wf(const float* __restrict__ wf1,
                                                 f16* __restrict__ Wf1b) {
    __shared__ __align__(16) f16 Wl[13][2848];
    int bid = blockIdx.x;          // 66 = 33 ks x 2 c
    int c = bid & 1, ks = bid >> 1;
    int tid = threadIdx.x;
    for (int e = tid; e < 89 * 32; e += 256) {
        int o = e >> 5, dl = e & 31;
        int d = ks * 32 + dl;
        if (d < 1029) {
            const float* p = wf1 + ((size_t)(c * 89 + o) * 1029 + d) * 13;
#pragma unroll
            for (int g = 0; g < 13; ++g) Wl[g][e] = (f16)p[g];
        } else {
#pragma unroll
            for (int g = 0; g < 13; ++g) Wl[g][e] = (f16)0;
        }
    }
    __syncthreads();
    for (int t = tid; t < 13 * 6 * 64; t += 256) {
        int l = t & 63; int q = t >> 6; int nt = q % 6; int g = q / 6;
        int o = nt * 16 + (l & 15);
        int kbase = (l >> 4) * 8;
        f16x8 v;
#pragma unroll
        for (int i = 0; i < 8; ++i)
            v[i] = (o < 89) ? Wl[g][o * 32 + kbase + i] : (f16)0;
        *(f16x8*)&Wf1b[(((size_t)ks * 26 + c * 13 + g) * 6 + nt) * 512 + (size_t)l * 8] = v;
    }
}

// ------------------------------------------------------------------
// K1: conv1 -> pool -> +bias -> trig expand (G=8) -> Tpre directly.
// (conv2m staging becomes a pure copy; trig leaves its critical path)
// ------------------------------------------------------------------
__global__ __launch_bounds__(256) void k_conv1(const float* __restrict__ x,
                                               const float* __restrict__ w1,
                                               const float* __restrict__ b1,
                                               f16* __restrict__ Tpre) {
    __shared__ float2 tcs[5][448];
    __shared__ float  cv[392 * 13];
    __shared__ float  bl[13];
    int bid = blockIdx.x, tid = threadIdx.x;
    int b = bid >> 1, yh = bid & 1;
    int y0 = yh * 12;
    const float* xb = x + (size_t)b * 784;
    if (tid < 13) bl[tid] = b1[tid];
    for (int i = tid; i < 448; i += 256) {
        float v = xb[y0 * 28 + i];
        float s1, c1; __sincosf(v, &s1, &c1);
        float ck = c1, sk = s1, ckm = 1.f, skm = 0.f;
#pragma unroll
        for (int g = 0; g < 5; ++g) {
            tcs[g][i] = make_float2(ck, sk);
            float cn = 2.f * c1 * ck - ckm, sn = 2.f * c1 * sk - skm;
            ckm = ck; ck = cn; skm = sk; sk = sn;
        }
    }
    __syncthreads();
    for (int pp = tid; pp < 392; pp += 256) {
        int yl = pp / 28, xx = pp % 28;
        int y = yh * 14 + yl;
        float acc[13] = {};
        for (int ky = 0; ky < 5; ++ky) {
            int row = y + ky - 2;
            if ((unsigned)row >= 28u) continue;
            int lr = row - y0;
            for (int kx = 0; kx < 5; ++kx) {
                int col = xx + kx - 2;
                if ((unsigned)col >= 28u) continue;
                float2 tv[5];
#pragma unroll
                for (int g = 0; g < 5; ++g) tv[g] = tcs[g][lr * 28 + col];
#pragma unroll
                for (int o = 0; o < 13; ++o) {
                    const float* wco = w1 + (o * 25 + ky * 5 + kx) * 5;
                    const float* wso = wco + 1625;
                    float a = acc[o];
#pragma unroll
                    for (int g = 0; g < 5; ++g)
                        a = fmaf(tv[g].x, wco[g], fmaf(tv[g].y, wso[g], a));
                    acc[o] = a;
                }
            }
        }
#pragma unroll
        for (int o = 0; o < 13; ++o) cv[pp * 13 + o] = acc[o];
    }
    __syncthreads();
    // (o, pyl, px) with px fastest -> coalesced 16B Tpre stores
    for (int i = tid; i < 13 * 7 * 14; i += 256) {
        int o = i / 98; int rem = i % 98; int pyl = rem / 14; int px = rem % 14;
        int base0 = ((pyl * 2) * 28 + px * 2) * 13 + o;
        float m = fmaxf(fmaxf(cv[base0], cv[base0 + 13]),
                        fmaxf(cv[base0 + 28 * 13], cv[base0 + 28 * 13 + 13]));
        int p = (yh * 7 + pyl) * 14 + px;
        float h = m + bl[o];
        float s1, c1; __sincosf(h, &s1, &c1);
        f16x8 vc, vs;
        float ck = c1, sk = s1, ckm = 1.f, skm = 0.f;
#pragma unroll
        for (int g = 0; g < 8; ++g) {
            vc[g] = (f16)ck; vs[g] = (f16)sk;
            float cn = 2.f * c1 * ck - ckm, sn = 2.f * c1 * sk - skm;
            ckm = ck; ck = cn; skm = sk; sk = sn;
        }
        *(f16x8*)&Tpre[((size_t)(b * 26 + o) * 196 + p) * 8] = vc;
        *(f16x8*)&Tpre[((size_t)(b * 26 + 13 + o) * 196 + p) * 8] = vs;
    }
}

// ------------------------------------------------------------------
// K2: conv2 mfma_32x32x16.  Block = (image, ky-PARITY).  Per (cg,kx)
// a wave holds bf[7] in regs: 49 MFMA / 13 ds_read (3.8x), 7-deep
// MFMA per A-read.  Staging is a pure Tpre->LDS copy.
// ------------------------------------------------------------------
template<int PAR>
__device__ __forceinline__ void conv2m_body(const f16* __restrict__ Tpre,
                                            const f16* __restrict__ Wb2,
                                            float* __restrict__ Pp,
                                            f16* Tl, int b) {
    const int tid = threadIdx.x;
    const int l = tid & 63, w = tid >> 6;
    const int oct = l >> 5;
    const int pyb = (l >> 4) & 1;
    const int px = l & 15;

    // zero halo once: cells (yy,oc,xx)
    for (int pos = tid; pos < 1792; pos += 256) {
        int yy2 = pos >> 5, xx = pos & 31;
        int yy = yy2 >> 1;
        if (yy < 6 || yy >= 20 || xx < 6 || xx >= 20) {
            f16x8 z = {};
            *(f16x8*)&Tl[(yy2 * 32 + xx) * 8] = z;
        }
    }

    f32x16 acc[7] = {};

    for (int cg = 0; cg < 13; ++cg) {
        if (cg) __syncthreads();
        // stage: pure 16B copy, coalesced reads, conflict-free writes
        for (int j = tid; j < 392; j += 256) {
            int oc = (j >= 196), p = j - oc * 196;
            int ch0 = cg * 16 + oc * 8;
            int c2 = ch0 / 104, rr = ch0 % 104, ii = rr >> 3;
            int ci = c2 * 13 + ii;
            f16x8 v = *(const f16x8*)&Tpre[((size_t)(b * 26 + ci) * 196 + p) * 8];
            int y = p / 14, xp = p - y * 14;
            *(f16x8*)&Tl[((((y + 6) * 2 + oc) * 32) + xp + 6) * 8] = v;
        }
        __syncthreads();

        const int j0 = (w + cg) & 3;
        for (int kxs = 0; kxs < 4; ++kxs) {
            const int kx = j0 + kxs * 4;
            if (kx > 12) break;            // uniform per wave
            f16x8 bf[7 - PAR];
#pragma unroll
            for (int t = 0; t < 7 - PAR; ++t) {
                int ky = PAR + 2 * t;
                bf[t] = *(const f16x8*)&Wb2[(((size_t)(cg * 13 + ky) * 13 + kx) * 64 + l) * 8];
            }
            const int xx = px + kx;
#pragma unroll
            for (int kp = 0; kp < 13 - PAR; ++kp) {
                const int yy = PAR + 2 * kp + pyb;
                f16x8 a = *(const f16x8*)&Tl[(((yy * 2 + oct) * 32) + xx) * 8];
#pragma unroll
                for (int t = 0; t < 7 - PAR; ++t) {
                    const int mt = kp - t;
                    if (mt >= 0 && mt <= 6)
                        acc[mt] = __builtin_amdgcn_mfma_f32_32x32x16_f16(a, bf[t], acc[mt], 0, 0, 0);
                }
            }
        }
    }

    // 4-wave LDS reduction into R[7][32][32] (reuses Tl)
    __syncthreads();
    float* R = (float*)Tl;
    for (int ph = 0; ph < 4; ++ph) {
        if (w == ph) {
#pragma unroll
            for (int mt = 0; mt < 7; ++mt)
#pragma unroll
                for (int reg = 0; reg < 16; ++reg) {
                    int row = (reg & 3) + 8 * (reg >> 2) + 4 * oct;
                    int idx = (mt * 32 + row) * 32 + (l & 31);
                    float v = acc[mt][reg];
                    if (ph) v += R[idx];
                    R[idx] = v;
                }
        }
        __syncthreads();
    }
    float* P = Pp + (size_t)(PAR * 256 + b) * 7168;
    for (int i = tid; i < 7168; i += 256) P[i] = R[i];
}

__global__ __launch_bounds__(256, 2) void k_conv2m(const f16* __restrict__ Tpre,
                                                   const f16* __restrict__ Wb2,
                                                   float* __restrict__ Pp) {
    __shared__ f16 Tl[28 * 2 * 32 * 8];   // 28,672 B
    int bid = blockIdx.x;
    int b = bid >> 1;
    if (bid & 1) conv2m_body<1>(Tpre, Wb2, Pp, Tl, b);
    else         conv2m_body<0>(Tpre, Wb2, Pp, Tl, b);
}

// ------------------------------------------------------------------
// K3: sum 2 parity partials + maxpool + bias -> h2f
// ------------------------------------------------------------------
__global__ __launch_bounds__(256) void k_pool2(const float* __restrict__ Pp,
                                               const float* __restrict__ b2,
                                               float* __restrict__ h2f) {
    int b = blockIdx.x, tid = threadIdx.x;
    for (int idx = tid; idx < 1029; idx += 256) {
        int o = idx % 21; int r = idx / 21; int px = r % 7; int py = r / 7;
        float mx = -1e30f;
#pragma unroll
        for (int sy = 0; sy < 2; ++sy)
#pragma unroll
            for (int sx = 0; sx < 2; ++sx) {
                int py2 = 2 * py + sy, px2 = 2 * px + sx;
                int mt = py2 >> 1, rr = (py2 & 1) * 16 + px2;
                float v = Pp[(size_t)b * 7168 + (mt * 32 + rr) * 32 + o]
                        + Pp[(size_t)(256 + b) * 7168 + (mt * 32 + rr) * 32 + o];
                mx = fmaxf(mx, v);
            }
        h2f[(size_t)b * 1029 + o * 49 + py * 7 + px] = mx + b2[o];
    }
}

// ------------------------------------------------------------------
// K4: fk1 via MFMA (unchanged).
// ------------------------------------------------------------------
__global__ __launch_bounds__(256) void k_fk1m(const float* __restrict__ h2f,
                                              const f16* __restrict__ Wf1b,
                                              float* __restrict__ P3) {
    __shared__ f16 A[26 * 32 * 32];
    const int bid = blockIdx.x;
    const int mt8 = bid / NCH, ks = bid % NCH;
    const int m0 = mt8 * 32, d0 = ks * 32;
    const int tid = threadIdx.x;
    const int dl = tid & 31, mb = tid >> 5;
#pragma unroll
    for (int j = 0; j < 4; ++j) {
        int m = mb + 8 * j;
        int d = d0 + dl;
        bool valid = d < 1029;
        float h = valid ? h2f[(size_t)(m0 + m) * 1029 + d] : 0.f;
        float s1, c1; __sincosf(h, &s1, &c1);
        float ck = c1, sk = s1, ckm = 1.f, skm = 0.f;
#pragma unroll
        for (int g = 0; g < 13; ++g) {
            A[(g) * 1024 + m * 32 + dl]      = valid ? (f16)ck : (f16)0;
            A[(13 + g) * 1024 + m * 32 + dl] = valid ? (f16)sk : (f16)0;
            float cn = 2.f * c1 * ck - ckm;
            float sn2 = 2.f * c1 * sk - skm;
            ckm = ck; ck = cn; skm = sk; sk = sn2;
        }
    }
    __syncthreads();
    const int w = tid >> 6, l = tid & 63;
    const int mt = w >> 1, ntg = (w & 1) * 3;
    f32x4 acc[3] = {};
    for (int kstep = 0; kstep < 26; ++kstep) {
        f16x8 a = *(const f16x8*)&A[kstep * 1024 + (mt * 16 + (l & 15)) * 32 + (l >> 4) * 8];
#pragma unroll
        for (int j = 0; j < 3; ++j) {
            f16x8 bv = *(const f16x8*)&Wf1b[((((size_t)ks * 26 + kstep) * 6 + ntg + j) * 64 + l) * 8];
            acc[j] = __builtin_amdgcn_mfma_f32_16x16x32_f16(a, bv, acc[j], 0, 0, 0);
        }
    }
    const int o_base = (l & 15);
#pragma unroll
    for (int j = 0; j < 3; ++j) {
        int o = (ntg + j) * 16 + o_base;
        if (o < 89) {
#pragma unroll
            for (int jj = 0; jj < 4; ++jj) {
                int m = m0 + mt * 16 + (l >> 4) * 4 + jj;
                P3[((size_t)ks * 256 + m) * 89 + o] = acc[j][jj];
            }
        }
    }
}

// ------------------------------------------------------------------
// K5: reduce 33 fk1 partials + bias -> trig(G=8) -> fk2 -> f32 out
// ------------------------------------------------------------------
__global__ __launch_bounds__(128) void k_fk2(const float* __restrict__ P3,
                                             const float* __restrict__ bias1,
                                             const float* __restrict__ wf2,
                                             const float* __restrict__ bias2,
                                             float* __restrict__ out) {
    __shared__ float2 tcs2[89][8];
    __shared__ float part[80];
    int b = blockIdx.x, tid = threadIdx.x;
    if (tid < 89) {
        float v = bias1[tid];
        for (int ks = 0; ks < NCH; ++ks)
            v += P3[((size_t)ks * 256 + b) * 89 + tid];
#pragma unroll
        for (int g = 0; g < 8; ++g) {
            float s, c; __sincosf(v * (float)(g + 1), &s, &c);
            tcs2[tid][g] = make_float2(c, s);
        }
    }
    __syncthreads();
    if (tid < 80) {
        int o = tid >> 3, g = tid & 7;
        float s = 0.f;
        for (int d = 0; d < 89; ++d) {
            float2 tv = tcs2[d][g];
            s = fmaf(tv.x, wf2[((size_t)o * 89 + d) * 8 + g],
                fmaf(tv.y, wf2[7120 + ((size_t)o * 89 + d) * 8 + g], s));
        }
        part[tid] = s;
    }
    __syncthreads();
    if (tid < 10) {
        float v = bias2[tid];
#pragma unroll
        for (int g = 0; g < 8; ++g) v += part[tid * 8 + g];
        out[b * 10 + tid] = v;
    }
}

extern "C" void kernel_launch(void* const* d_in, const int* in_sizes, int n_in,
                              void* d_out, int out_size, void* d_ws, size_t ws_size,
                              hipStream_t stream) {
    const float* x   = (const float*)d_in[0];
    const float* w1  = (const float*)d_in[1];
    const float* b1  = (const float*)d_in[2];
    const float* w2  = (const float*)d_in[3];
    const float* b2  = (const float*)d_in[4];
    const float* wf1 = (const float*)d_in[5];
    const float* bf1 = (const float*)d_in[6];
    const float* wf2 = (const float*)d_in[7];
    const float* bf2v = (const float*)d_in[8];

    char* ws  = (char*)d_ws;
    f16*   Tpre = (f16*)(ws + TP_OFF);
    f16*   Wb2  = (f16*)(ws + WB_OFF);
    f16*   Wf1b = (f16*)(ws + WF_OFF);
    float* Pp   = (float*)(ws + PP_OFF);
    float* h2f  = (float*)(ws + H2_OFF);
    float* P3   = (float*)(ws + P3_OFF);

    k_prep_wb<<<(2197 * 64 + 255) / 256, 256, 0, stream>>>(w2, Wb2);
    k_prep_wf<<<66, 256, 0, stream>>>(wf1, Wf1b);
    k_conv1<<<512, 256, 0, stream>>>(x, w1, b1, Tpre);
    k_conv2m<<<512, 256, 0, stream>>>(Tpre, Wb2, Pp);
    k_pool2<<<256, 256, 0, stream>>>(Pp, b2, h2f);
    k_fk1m<<<8 * NCH, 256, 0, stream>>>(h2f, Wf1b, P3);
    k_fk2<<<256, 128, 0, stream>>>(P3, bf1, wf2, bf2v, (float*)d_out);
}